// Round 5
// baseline (750.497 us; speedup 1.0000x reference)
//
#include <hip/hip_runtime.h>
#include <hip/hip_bf16.h>

// GroupGMM: B=8192, I=512, G=32, C=16, D=32; out = concat(pi[16], mu[512], softplus(sig)[512])
#define BATCH 8192
#define IDIM  512
#define GDIM  32
#define NOUT  1040
#define NPAD  1152     // 9 * 128 n-tiles
#define KW    16384    // G*I
#define BM    64
#define BN    128
#define NCH   256      // K-chunks: 32 groups x 8 chunks (K=64 each)

typedef short bf16x8 __attribute__((ext_vector_type(8)));   // 8 bf16 (4 VGPRs)
typedef float floatx4 __attribute__((ext_vector_type(4)));  // MFMA acc

__device__ inline unsigned pk2(float a, float b) {
    union { __hip_bfloat162 h2; unsigned u; } cv;
    cv.h2 = __float22bfloat162_rn(float2{a, b});
    return cv.u;
}

// ---- cvt fp32 -> bf16, 8 elems/thread (xb and gb) ---------------------------------
__global__ void cvt_bf16(const float* __restrict__ s, unsigned short* __restrict__ d) {
    int t = blockIdx.x * 256 + threadIdx.x;
    const float4* sp = (const float4*)s + (size_t)t * 2;
    float4 a = sp[0], b = sp[1];
    uint4 p;
    p.x = pk2(a.x, a.y); p.y = pk2(a.z, a.w);
    p.z = pk2(b.x, b.y); p.w = pk2(b.z, b.w);
    *(uint4*)(d + (size_t)t * 8) = p;
}

// ---- prep: Wt[n][16384] bf16 (weights only; zero-padded rows n>=1040) -------------
__global__ void prep_wt(const float* __restrict__ Wmu, const float* __restrict__ Wsig,
                        const float* __restrict__ Wpi, unsigned short* __restrict__ Wt) {
    int n = blockIdx.y * 256 + threadIdx.x;
    if (n >= NPAD) return;
    int k0 = blockIdx.x * 8;
    float v[8];
#pragma unroll
    for (int j = 0; j < 8; ++j) {
        int k = k0 + j, gg = k >> 9, i = k & 511;
        float val = 0.0f;
        if (n < 16)         val = Wpi [(gg * 512 + i) * 16  + n];
        else if (n < 528)   val = Wmu [(gg * 512 + i) * 512 + (n - 16)];
        else if (n < NOUT)  val = Wsig[(gg * 512 + i) * 512 + (n - 528)];
        v[j] = val;
    }
    uint4 p;
    p.x = pk2(v[0], v[1]); p.y = pk2(v[2], v[3]);
    p.z = pk2(v[4], v[5]); p.w = pk2(v[6], v[7]);
    *(uint4*)&Wt[(size_t)n * KW + k0] = p;
}

// ---- prep: Wb[n][32] bf16 = concatenated biases, n-major --------------------------
__global__ void prep_wb(const float* __restrict__ bmu, const float* __restrict__ bsig,
                        const float* __restrict__ bpi, unsigned short* __restrict__ Wb) {
    int n = blockIdx.y * 256 + threadIdx.x;
    if (n >= NPAD) return;
    int k0 = blockIdx.x * 8;
    float v[8];
#pragma unroll
    for (int j = 0; j < 8; ++j) {
        int gg = k0 + j;
        float val = 0.0f;
        if (n < 16)         val = bpi [gg * 16  + n];
        else if (n < 528)   val = bmu [gg * 512 + (n - 16)];
        else if (n < NOUT)  val = bsig[gg * 512 + (n - 528)];
        v[j] = val;
    }
    uint4 p;
    p.x = pk2(v[0], v[1]); p.y = pk2(v[2], v[3]);
    p.z = pk2(v[4], v[5]); p.w = pk2(v[6], v[7]);
    *(uint4*)&Wb[(size_t)n * GDIM + k0] = p;
}

// ---- GEMM: barrier-free K-loop. A (64x512) resident in LDS; B streamed to VGPRs ---
// out[m,n] = sum_gg g[m,gg]*(xb[m,gg-slice] @ Wt_gg[:,n]) + gb[m,:] @ Wb[:,n]^T
__global__ __launch_bounds__(256, 2) void gemm_gmm(
        const unsigned short* __restrict__ xb, const unsigned short* __restrict__ gb,
        const float* __restrict__ g, const unsigned short* __restrict__ Wt,
        const unsigned short* __restrict__ Wb, float* __restrict__ out) {
    __shared__ unsigned short lA[BM * IDIM];   // 64 KB, XOR-swizzled 16B granules
    __shared__ float gsc[GDIM * BM];           // 8 KB: gsc[gg*64+row] = g[m0+row][gg]
    __shared__ unsigned short lG[BM * 40];     // 5 KB: bias A-tile, +8 pad stride

    const int t = threadIdx.x, lane = t & 63, w = t >> 6;
    const int wn = w * 32;                     // each wave owns 64m x 32n
    const int q = lane >> 4, l15 = lane & 15;
    const int m0 = blockIdx.x * BM, n0 = blockIdx.y * BN;

    // ---- prologue: A tile, scales, bias tile -> LDS (one barrier total) ----------
    {
        const int r = t >> 2, c4 = t & 3;      // 4 threads per row
        const uint4* src = (const uint4*)(xb + (size_t)(m0 + r) * IDIM);
#pragma unroll
        for (int j = 0; j < 16; ++j) {
            int gi = c4 + 4 * j;               // granule index 0..63
            uint4 v = src[gi];
            *(uint4*)&lA[(r * 64 + (gi ^ (r & 7))) * 8] = v;
        }
#pragma unroll
        for (int j = 0; j < 8; ++j) {
            int idx = t * 8 + j;               // [gg][row]
            int gg = idx >> 6, row = idx & 63;
            gsc[idx] = g[(size_t)(m0 + row) * GDIM + gg];
        }
        *(uint4*)&lG[(t >> 2) * 40 + (t & 3) * 8] =
            *(const uint4*)(gb + (size_t)(m0 + (t >> 2)) * GDIM + (t & 3) * 8);
    }
    __syncthreads();

    // ---- B row bases (per tn): 16B-contiguous k-runs of n-major Wt ---------------
    size_t browB[2];
#pragma unroll
    for (int tn = 0; tn < 2; ++tn)
        browB[tn] = (size_t)(n0 + wn + tn * 16 + l15) * KW + q * 8;

    uint4 breg[4][2][2];                       // [slot][ks][tn]
    auto loadB = [&](int c, int slot) {
#pragma unroll
        for (int ks = 0; ks < 2; ++ks)
#pragma unroll
            for (int tn = 0; tn < 2; ++tn)
                breg[slot][ks][tn] = *(const uint4*)(Wt + browB[tn] + c * 64 + ks * 32);
    };

    floatx4 acc[4][2] = {};
    floatx4 P[4][2] = {};

    loadB(0, 0); loadB(1, 1); loadB(2, 2);     // prefetch depth 3

    const int swA = l15 & 7;                   // A-read swizzle key (row&7 == l15&7)
    for (int cc = 0; cc < NCH; cc += 4) {
#pragma unroll
        for (int s = 0; s < 4; ++s) {
            const int c = cc + s;
            if (c + 3 < NCH) loadB(c + 3, (s + 3) & 3);   // wave-uniform branch
            const int ac8 = (c & 7) * 8;
#pragma unroll
            for (int ks = 0; ks < 2; ++ks) {
                bf16x8 af[4];
#pragma unroll
                for (int tm = 0; tm < 4; ++tm) {
                    int gi = ac8 + ks * 4 + q;
                    af[tm] = *(const bf16x8*)&lA[((tm * 16 + l15) * 64 + (gi ^ swA)) * 8];
                }
#pragma unroll
                for (int tm = 0; tm < 4; ++tm)
#pragma unroll
                    for (int tn = 0; tn < 2; ++tn)
                        P[tm][tn] = __builtin_amdgcn_mfma_f32_16x16x32_bf16(
                            af[tm], *(const bf16x8*)&breg[s][ks][tn], P[tm][tn], 0, 0, 0);
            }
            if ((c & 7) == 7) {                // group boundary: acc += g[m,gg]*P
                const int gg = c >> 3;
#pragma unroll
                for (int tm = 0; tm < 4; ++tm) {
                    floatx4 s4 = *(const floatx4*)&gsc[gg * 64 + tm * 16 + q * 4];
#pragma unroll
                    for (int tn = 0; tn < 2; ++tn) {
#pragma unroll
                        for (int r = 0; r < 4; ++r)
                            acc[tm][tn][r] += s4[r] * P[tm][tn][r];
                        P[tm][tn] = (floatx4){0.f, 0.f, 0.f, 0.f};
                    }
                }
            }
        }
    }

    // ---- bias: one K=32 MFMA per (tm,tn), folded straight into acc ---------------
    {
        bf16x8 afb[4], bb[2];
#pragma unroll
        for (int tm = 0; tm < 4; ++tm)
            afb[tm] = *(const bf16x8*)&lG[(tm * 16 + l15) * 40 + q * 8];
#pragma unroll
        for (int tn = 0; tn < 2; ++tn)
            bb[tn] = *(const bf16x8*)(Wb + (size_t)(n0 + wn + tn * 16 + l15) * GDIM + q * 8);
#pragma unroll
        for (int tm = 0; tm < 4; ++tm)
#pragma unroll
            for (int tn = 0; tn < 2; ++tn)
                acc[tm][tn] = __builtin_amdgcn_mfma_f32_16x16x32_bf16(
                    afb[tm], bb[tn], acc[tm][tn], 0, 0, 0);
    }

    // ---- epilogue: fused softplus on sigma region, direct store ------------------
#pragma unroll
    for (int tn = 0; tn < 2; ++tn) {
        int n = n0 + wn + tn * 16 + l15;
        if (n >= NOUT) continue;
        bool is_scale = (n >= 528);
#pragma unroll
        for (int tm = 0; tm < 4; ++tm) {
            int mbase = m0 + tm * 16 + q * 4;
#pragma unroll
            for (int r = 0; r < 4; ++r) {
                float vv = acc[tm][tn][r];
                if (is_scale) {
                    float sp = (vv > 15.0f) ? vv : log1pf(expf(vv));
                    vv = sp + 1e-7f;
                }
                out[(size_t)(mbase + r) * NOUT + n] = vv;
            }
        }
    }
}

extern "C" void kernel_launch(void* const* d_in, const int* in_sizes, int n_in,
                              void* d_out, int out_size, void* d_ws, size_t ws_size,
                              hipStream_t stream) {
    const float* x    = (const float*)d_in[0];
    const float* g    = (const float*)d_in[1];
    const float* Wmu  = (const float*)d_in[2];
    const float* bmu  = (const float*)d_in[3];
    const float* Wsig = (const float*)d_in[4];
    const float* bsig = (const float*)d_in[5];
    const float* Wpi  = (const float*)d_in[6];
    const float* bpi  = (const float*)d_in[7];
    float* out = (float*)d_out;

    // workspace (~46.3 MB)
    char* ws = (char*)d_ws;
    unsigned short* Wt = (unsigned short*)ws;  ws += (size_t)NPAD * KW * 2;     // 37.75 MB
    unsigned short* xb = (unsigned short*)ws;  ws += (size_t)BATCH * IDIM * 2;  //  8.0 MB
    unsigned short* gb = (unsigned short*)ws;  ws += (size_t)BATCH * GDIM * 2;  //  0.5 MB
    unsigned short* Wb = (unsigned short*)ws;                                   //  0.07 MB

    cvt_bf16<<<BATCH * IDIM / 2048, 256, 0, stream>>>(x, xb);
    cvt_bf16<<<BATCH * GDIM / 2048, 256, 0, stream>>>(g, gb);
    prep_wt<<<dim3(KW / 8, 5), 256, 0, stream>>>(Wmu, Wsig, Wpi, Wt);
    prep_wb<<<dim3(GDIM / 8, 5), 256, 0, stream>>>(bmu, bsig, bpi, Wb);
    gemm_gmm<<<dim3(BATCH / BM, NPAD / BN), 256, 0, stream>>>(xb, gb, g, Wt, Wb, out);
}